// Round 2
// baseline (8931.995 us; speedup 1.0000x reference)
//
#include <hip/hip_runtime.h>

// Decoder: 2-layer LSTM, B=1024, IN=256, H=512, OUT=256, T2=128 (hardcoded).
// PERSISTENT kernel, 512 blocks x 256 thr, 2 blocks/CU (66KB LDS each).
// Round-5 structure (resubmit after infra failure, +slot clamp hardening):
// 32 batch-groups of 32 rows, 16 j-blocks each, XCD-LOCAL (4 groups per XCD).
// Two independent group-chains share each CU so one chain's barrier/load
// waits overlap the other's MFMAs (latency-bound fix).
//   - blocks read HW_REG_XCC_ID and self-assign (group, j) via per-XCD atomic
//     counters => correctness never depends on blockIdx->XCD mapping.
//   - activations (h0, h1, z) exchanged through the XCD's own L2: plain
//     write-back stores + plain cached loads; freshness via per-CU buffer_inv
//     (L1-only, L2 untouched) at each 16-block group barrier.
//   - weights pre-swizzled to MFMA B-frag order (layouts unchanged); each
//     block parks fc/lin slice (+1 cell1 B-tile for j>=8) in LDS permanently.
//   - c-state in VGPRs. Barriers: per-group monotone counter on its own
//     cacheline, agent atomics.

typedef __attribute__((ext_vector_type(8))) __bf16 bf16x8;
typedef __attribute__((ext_vector_type(16))) float f32x16;
typedef unsigned long long ull;

__device__ __forceinline__ f32x16 mfma_bf16(bf16x8 a, bf16x8 b, f32x16 c) {
  return __builtin_amdgcn_mfma_f32_32x32x16_bf16(a, b, c, 0, 0, 0);
}

__device__ __forceinline__ short f2bf(float f) {  // RNE fp32->bf16
  unsigned u = __float_as_uint(f);
  u += 0x7fffu + ((u >> 16) & 1u);
  return (short)(u >> 16);
}

__device__ __forceinline__ float sigm(float x) { return 1.0f / (1.0f + __expf(-x)); }
__device__ __forceinline__ float tanh_fast(float x) { return 2.0f / (1.0f + __expf(-2.0f * x)) - 1.0f; }

__device__ __forceinline__ f32x16 zero16() {
  f32x16 z;
#pragma unroll
  for (int i = 0; i < 16; ++i) z[i] = 0.0f;
  return z;
}

// A-tile LDS layout: row m (0..31) at stride 132 shorts.
#define AT_STRIDE 132
#define AT_WORDS (32 * AT_STRIDE)  // 4224 shorts = 8448 B per tile

// ---------------------------------------------------------------------------
// prep: swizzle weights into per-(j, k16-step, gate) lane-contiguous MFMA
// B-fragments; sum biases; init bf16 states; zero barrier flags + XCD ctrs.
// (Weight layouts are row-count independent — identical to round-4.)
// ---------------------------------------------------------------------------
__global__ __launch_bounds__(256) void prep_kernel(
    const float* __restrict__ z0, const float* __restrict__ h0in,
    const float* __restrict__ Wih0, const float* __restrict__ Whh0,
    const float* __restrict__ bih0, const float* __restrict__ bhh0,
    const float* __restrict__ Wih1, const float* __restrict__ Whh1,
    const float* __restrict__ bih1, const float* __restrict__ bhh1,
    const float* __restrict__ fcW, const float* __restrict__ linW,
    short* __restrict__ wsw0, short* __restrict__ wsw1,
    short* __restrict__ fcWsw, short* __restrict__ linWsw,
    float* __restrict__ bias0, float* __restrict__ bias1,
    short* __restrict__ zb1, short* __restrict__ h0b0, short* __restrict__ h1b0,
    int* __restrict__ flags)
{
  int idx = blockIdx.x * 256 + threadIdx.x;
  if (idx < 1572864) {  // wsw0 [j16][s48][g4][l64][8]; K=768 = [z 256 | h0 512]
    int jj = idx & 7, l = (idx >> 3) & 63, gg = (idx >> 9) & 3;
    int rest = idx >> 11;           // j*48 + s
    int s = rest % 48, b = rest / 48;
    int row = gg * 512 + b * 32 + (l & 31);
    int k = s * 16 + (l >> 5) * 8 + jj;
    wsw0[idx] = f2bf(k < 256 ? Wih0[row * 256 + k] : Whh0[row * 512 + (k - 256)]);
    return;
  }
  idx -= 1572864;
  if (idx < 2097152) {  // wsw1 [j16][s64][g4][l64][8]; K=1024 = [h0 512 | h1 512]
    int jj = idx & 7, l = (idx >> 3) & 63, gg = (idx >> 9) & 3;
    int rest = idx >> 11;           // j*64 + s
    int s = rest & 63, b = rest >> 6;
    int row = gg * 512 + b * 32 + (l & 31);
    int k = s * 16 + (l >> 5) * 8 + jj;
    wsw1[idx] = f2bf(k < 512 ? Wih1[row * 512 + k] : Whh1[row * 512 + (k - 512)]);
    return;
  }
  idx -= 2097152;
  if (idx < 131072) {  // fcWsw [jz8][s32][l64][8]
    int jj = idx & 7, l = (idx >> 3) & 63, s = (idx >> 9) & 31, jz = idx >> 14;
    int col = jz * 32 + (l & 31);
    int k = s * 16 + (l >> 5) * 8 + jj;
    fcWsw[idx] = f2bf(fcW[col * 512 + k]);
    return;
  }
  idx -= 131072;
  if (idx < 65536) {  // linWsw [jo8][s16][l64][8]
    int jj = idx & 7, l = (idx >> 3) & 63, s = (idx >> 9) & 15, jo = idx >> 13;
    int col = jo * 32 + (l & 31);
    int k = s * 16 + (l >> 5) * 8 + jj;
    linWsw[idx] = f2bf(linW[col * 256 + k]);
    return;
  }
  idx -= 65536;
  if (idx < 2048) { bias0[idx] = bih0[idx] + bhh0[idx]; return; }
  idx -= 2048;
  if (idx < 2048) { bias1[idx] = bih1[idx] + bhh1[idx]; return; }
  idx -= 2048;
  if (idx < 262144) { zb1[idx] = f2bf(z0[idx]); return; }
  idx -= 262144;
  if (idx < 524288) { h0b0[idx] = f2bf(h0in[idx]); return; }
  idx -= 524288;
  if (idx < 524288) { h1b0[idx] = f2bf(h0in[524288 + idx]); return; }
  idx -= 524288;
  if (idx < 2048) { flags[idx] = 0; return; }  // [g*32] group flags, [1024+x*32] xcd ctrs
}

// ---------------------------------------------------------------------------
// Group barrier: 16 same-XCD blocks, monotone counter (one cacheline per
// group). buffer_inv = per-CU vector-L1 invalidate only (L2 stays warm).
// ---------------------------------------------------------------------------
__device__ __forceinline__ void group_barrier(int* flag, int target) {
  asm volatile("s_waitcnt vmcnt(0)" ::: "memory");
  __syncthreads();
  if (threadIdx.x == 0) {
    __hip_atomic_fetch_add(flag, 1, __ATOMIC_RELAXED, __HIP_MEMORY_SCOPE_AGENT);
    while (__hip_atomic_load(flag, __ATOMIC_RELAXED, __HIP_MEMORY_SCOPE_AGENT) < target)
      __builtin_amdgcn_s_sleep(4);
    asm volatile("buffer_inv" ::: "memory");
  }
  __syncthreads();
}

// one K128 tile of MFMA: 8 x (A from LDS, B from bt — LDS or global)
__device__ __forceinline__ void mfma_k128(const short* at, const short* bt,
                                          f32x16& acc, int gq, int l,
                                          int ln, int kh) {
#pragma unroll
  for (int s = 0; s < 8; ++s) {
    bf16x8 a = *(const bf16x8*)&at[ln * AT_STRIDE + (s * 2 + kh) * 8];
    bf16x8 b = *(const bf16x8*)&bt[((s * 4 + gq) * 64 + l) * 8];
    acc = mfma_bf16(a, b, acc);
  }
}

// ---------------------------------------------------------------------------
// LSTM cell phase (M=32): gates = [A|B panels] @ W^T + bias; c in regs;
// h -> plain store (same-XCD L2). First NLDS B-tiles come from LDS cache.
// ---------------------------------------------------------------------------
template <int NT, int TA, int NLDS>
__device__ __forceinline__ void cell_phase(
    short* At0, short* At1, float* gbuf,
    const short* __restrict__ srcA, int ldA,
    const short* __restrict__ srcB, int ldB,
    const short* wlds, const short* __restrict__ wglob,
    const float* __restrict__ bias,
    float* cr, short* hout, int row0, int j0)
{
  const int t = threadIdx.x;          // 0..255, 4 waves
  const int gq = t >> 6, l = t & 63;  // wave = gate quadrant
  const int ln = l & 31, kh = l >> 5;
  const int sks = t & 15, sm = t >> 4;   // staging: ks 0..15, m 0..15 (+16)
  short* Abuf[2] = {At0, At1};
  f32x16 acc = zero16();
  uint4 pre[2];
#pragma unroll
  for (int i = 0; i < 2; ++i)
    pre[i] = *(const uint4*)&srcA[(row0 + sm + 16 * i) * ldA + sks * 8];
#pragma unroll
  for (int i = 0; i < 2; ++i)
    *(uint4*)&Abuf[0][(sm + 16 * i) * AT_STRIDE + sks * 8] = pre[i];
  __syncthreads();
#pragma unroll
  for (int tau = 0; tau < NT; ++tau) {
    if (tau + 1 < NT) {
      const short* src; int ld, col;
      if (tau + 1 < TA) { src = srcA; ld = ldA; col = (tau + 1) * 128; }
      else              { src = srcB; ld = ldB; col = (tau + 1 - TA) * 128; }
#pragma unroll
      for (int i = 0; i < 2; ++i)
        pre[i] = *(const uint4*)&src[(row0 + sm + 16 * i) * ld + col + sks * 8];
    }
    const short* at = Abuf[tau & 1];
    if (tau < NLDS) mfma_k128(at, wlds + tau * 16384, acc, gq, l, ln, kh);
    else            mfma_k128(at, wglob + tau * 16384, acc, gq, l, ln, kh);
    if (tau + 1 < NT) {
      short* nxt = Abuf[(tau + 1) & 1];
#pragma unroll
      for (int i = 0; i < 2; ++i)
        *(uint4*)&nxt[(sm + 16 * i) * AT_STRIDE + sks * 8] = pre[i];
    }
    __syncthreads();
  }
  // C layout: col = lane&31, row = (r&3)+8*(r>>2)+4*(lane>>5). gbuf aliases At.
#pragma unroll
  for (int r = 0; r < 16; ++r) {
    int mloc = (r & 3) + 8 * (r >> 2) + 4 * kh;
    gbuf[(gq * 32 + mloc) * 32 + ln] = acc[r];
  }
  __syncthreads();
  const int m = t >> 3, nb = (t & 7) * 4;  // m 0..31, nb 0..28
  short hh[4];
#pragma unroll
  for (int u = 0; u < 4; ++u) {
    int n = nb + u, jn = j0 + n;
    float gi = gbuf[(0 * 32 + m) * 32 + n] + bias[jn];
    float gf = gbuf[(1 * 32 + m) * 32 + n] + bias[512 + jn];
    float gg = gbuf[(2 * 32 + m) * 32 + n] + bias[1024 + jn];
    float go = gbuf[(3 * 32 + m) * 32 + n] + bias[1536 + jn];
    float cn = sigm(gf) * cr[u] + sigm(gi) * tanh_fast(gg);
    cr[u] = cn;
    hh[u] = f2bf(sigm(go) * tanh_fast(cn));
  }
  ull hv; __builtin_memcpy(&hv, hh, 8);
  *(ull*)&hout[(size_t)(row0 + m) * 512 + j0 + nb] = hv;  // plain: same-XCD L2
}

// ---------------------------------------------------------------------------
// Projection partials (fc or lin): B entirely from LDS cache. Waves = kq
// (K-partial); 4 K-partials land in gbuf[kq][m][n] for combine.
// ---------------------------------------------------------------------------
template <int NQ>
__device__ __forceinline__ void proj_partials(
    short* At0, float* gbuf,
    const short* __restrict__ src, int ld,
    const short* wblk, int row0)
{
  const int t = threadIdx.x;
  const int kq = t >> 6, l = t & 63;
  const int ln = l & 31, kh = l >> 5;
  const int sks = t & 15, sm = t >> 4;
  f32x16 acc = zero16();
#pragma unroll
  for (int q = 0; q < NQ; ++q) {
    __syncthreads();
    uint4 pre[2];
#pragma unroll
    for (int i = 0; i < 2; ++i)
      pre[i] = *(const uint4*)&src[(row0 + sm + 16 * i) * ld + q * 128 + sks * 8];
#pragma unroll
    for (int i = 0; i < 2; ++i)
      *(uint4*)&At0[(sm + 16 * i) * AT_STRIDE + sks * 8] = pre[i];
    __syncthreads();
#pragma unroll
    for (int sl = 0; sl < 2; ++sl) {
      int s16 = kq * 2 + sl;
      bf16x8 a = *(const bf16x8*)&At0[ln * AT_STRIDE + (s16 * 2 + kh) * 8];
      bf16x8 b = *(const bf16x8*)&wblk[((q * 8 + s16) * 64 + l) * 8];
      acc = mfma_bf16(a, b, acc);
    }
  }
  __syncthreads();
#pragma unroll
  for (int r = 0; r < 16; ++r) {
    int mloc = (r & 3) + 8 * (r >> 2) + 4 * kh;
    gbuf[(kq * 32 + mloc) * 32 + ln] = acc[r];
  }
  __syncthreads();
}

__global__ __launch_bounds__(256, 2) void decoder_persist(
    const short* __restrict__ wsw0, const short* __restrict__ wsw1,
    const short* __restrict__ fcWsw, const short* __restrict__ linWsw,
    const float* __restrict__ bias0, const float* __restrict__ bias1,
    const float* __restrict__ fcb, const float* __restrict__ linb,
    const float* __restrict__ c0in,
    short* h0x, short* h0y, short* h1x, short* h1y, short* zx, short* zy,
    int* flags, float* __restrict__ outp)
{
  __shared__ __align__(16) char arena[2 * AT_WORDS * 2];  // 16896 B (A dbuf / gbuf)
  __shared__ __align__(16) short wc[24576];               // 49152 B weight cache
  __shared__ int sgj[2];
  short* At0 = (short*)arena;
  short* At1 = At0 + AT_WORDS;
  float* gbuf = (float*)arena;   // 16384 B, aliases the A tiles

  // --- self-assignment: physical XCD id -> (group, j) slot ---
  if (threadIdx.x == 0) {
    unsigned xcc;
    asm volatile("s_getreg_b32 %0, hwreg(HW_REG_XCC_ID, 0, 32)" : "=s"(xcc));
    xcc &= 7u;
    int slot = __hip_atomic_fetch_add(&flags[1024 + (int)xcc * 32], 1,
                                      __ATOMIC_RELAXED, __HIP_MEMORY_SCOPE_AGENT);
    slot &= 63;                           // hardening: wrong-answer > hang
    sgj[0] = (int)xcc * 4 + (slot >> 4);  // group: 4 per XCD
    sgj[1] = slot & 15;                   // j-tile within group
  }
  __syncthreads();
  const int g = sgj[0], j = sgj[1];
  const int row0 = g * 32, j0 = j * 32;
  int* flag = &flags[g * 32];             // one cacheline per group

  // --- park fc/lin slice (+1 cell1 B-tile for j>=8) in LDS, loaded once ---
  if (j < 8) {
    const short* s1 = fcWsw + j * 16384;
    for (int i = threadIdx.x; i < 2048; i += 256)
      *(uint4*)&wc[i * 8] = *(const uint4*)&s1[i * 8];
  } else {
    const short* s1 = linWsw + (j - 8) * 8192;
    for (int i = threadIdx.x; i < 1024; i += 256)
      *(uint4*)&wc[i * 8] = *(const uint4*)&s1[i * 8];
    const short* s2 = wsw1 + j * 131072;
    for (int i = threadIdx.x; i < 2048; i += 256)   // 1 tile
      *(uint4*)&wc[8192 + i * 8] = *(const uint4*)&s2[i * 8];
  }
  const short* wl1 = wc + 8192;  // valid only for j>=8 (NLDS=1)
  __syncthreads();

  // --- c-state in registers for the whole run ---
  float c0r[4], c1r[4];
  {
    const int m = threadIdx.x >> 3, nb = (threadIdx.x & 7) * 4;
#pragma unroll
    for (int u = 0; u < 4; ++u) {
      c0r[u] = c0in[(size_t)(row0 + m) * 512 + j0 + nb + u];
      c1r[u] = c0in[524288 + (size_t)(row0 + m) * 512 + j0 + nb + u];
    }
  }

  short* h0buf[2] = {h0x, h0y};
  short* h1buf[2] = {h1x, h1y};
  short* zbuf[2] = {zx, zy};
  const short* wg0 = wsw0 + j * 98304;
  const short* wg1 = wsw1 + j * 131072;

  int target = 0;
#pragma unroll 1
  for (int t = 0; t < 128; ++t) {
    const int p = t & 1;
    // P1: cell0  (K = [z 256 | h0 512])
    cell_phase<6, 2, 0>(At0, At1, gbuf, zbuf[p ^ 1], 256, h0buf[p], 512,
                        nullptr, wg0, bias0, c0r, h0buf[p ^ 1], row0, j0);
    target += 16; group_barrier(flag, target);
    // P2: cell1  (K = [h0_new 512 | h1 512]); j>=8: first B-tile from LDS
    if (j < 8)
      cell_phase<8, 4, 0>(At0, At1, gbuf, h0buf[p ^ 1], 512, h1buf[p], 512,
                          wl1, wg1, bias1, c1r, h1buf[p ^ 1], row0, j0);
    else
      cell_phase<8, 4, 1>(At0, At1, gbuf, h0buf[p ^ 1], 512, h1buf[p], 512,
                          wl1, wg1, bias1, c1r, h1buf[p ^ 1], row0, j0);
    target += 16; group_barrier(flag, target);
    // P3: j<8 -> z(t) = fc(h1); j>=8 -> out(t-1) = lin(z(t-1))
    if (j < 8) {
      proj_partials<4>(At0, gbuf, h1buf[p ^ 1], 512, wc, row0);
      const int m = threadIdx.x >> 3, nb = (threadIdx.x & 7) * 4;
      const int n0 = j * 32;
      short zz[4];
#pragma unroll
      for (int u = 0; u < 4; ++u) {
        int n = nb + u;
        float v = gbuf[(0 * 32 + m) * 32 + n] + gbuf[(1 * 32 + m) * 32 + n] +
                  gbuf[(2 * 32 + m) * 32 + n] + gbuf[(3 * 32 + m) * 32 + n] +
                  fcb[n0 + n];
        zz[u] = f2bf(v);
      }
      ull zv; __builtin_memcpy(&zv, zz, 8);
      *(ull*)&zbuf[p][(size_t)(row0 + m) * 256 + n0 + nb] = zv;
    } else if (t > 0) {
      proj_partials<2>(At0, gbuf, zbuf[p ^ 1], 256, wc, row0);
      const int m = threadIdx.x >> 3, nb = (threadIdx.x & 7) * 4;
      const int n0 = (j - 8) * 32;
      float4 ov;
      float* po = &ov.x;
#pragma unroll
      for (int u = 0; u < 4; ++u) {
        int n = nb + u;
        po[u] = gbuf[(0 * 32 + m) * 32 + n] + gbuf[(1 * 32 + m) * 32 + n] +
                gbuf[(2 * 32 + m) * 32 + n] + gbuf[(3 * 32 + m) * 32 + n] +
                linb[n0 + n];
      }
      *(float4*)&outp[(size_t)(t - 1) * 262144 + (size_t)(row0 + m) * 256 + n0 + nb] = ov;
    }
    target += 16; group_barrier(flag, target);
  }
  // final out(127) from z(127) in zbuf[1]
  if (j >= 8) {
    proj_partials<2>(At0, gbuf, zbuf[1], 256, wc, row0);
    const int m = threadIdx.x >> 3, nb = (threadIdx.x & 7) * 4;
    const int n0 = (j - 8) * 32;
    float4 ov;
    float* po = &ov.x;
#pragma unroll
    for (int u = 0; u < 4; ++u) {
      int n = nb + u;
      po[u] = gbuf[(0 * 32 + m) * 32 + n] + gbuf[(1 * 32 + m) * 32 + n] +
              gbuf[(2 * 32 + m) * 32 + n] + gbuf[(3 * 32 + m) * 32 + n] +
              linb[n0 + n];
    }
    *(float4*)&outp[(size_t)127 * 262144 + (size_t)(row0 + m) * 256 + n0 + nb] = ov;
  }
}

// ---------------------------------------------------------------------------
extern "C" void kernel_launch(void* const* d_in, const int* in_sizes, int n_in,
                              void* d_out, int out_size, void* d_ws, size_t ws_size,
                              hipStream_t stream) {
  const float* z0   = (const float*)d_in[0];
  const float* h0in = (const float*)d_in[1];
  const float* c0in = (const float*)d_in[2];
  const float* Wih0 = (const float*)d_in[3];
  const float* Whh0 = (const float*)d_in[4];
  const float* bih0 = (const float*)d_in[5];
  const float* bhh0 = (const float*)d_in[6];
  const float* Wih1 = (const float*)d_in[7];
  const float* Whh1 = (const float*)d_in[8];
  const float* bih1 = (const float*)d_in[9];
  const float* bhh1 = (const float*)d_in[10];
  const float* fcW  = (const float*)d_in[11];
  const float* fcb  = (const float*)d_in[12];
  const float* linW = (const float*)d_in[13];
  const float* linb = (const float*)d_in[14];
  float* out = (float*)d_out;

  char* ws = (char*)d_ws;
  short* wsw0  = (short*)(ws + 0);         // 3,145,728 B
  short* wsw1  = (short*)(ws + 3145728);   // 4,194,304 B
  short* fcWsw = (short*)(ws + 7340032);   //   262,144 B
  short* linWsw= (short*)(ws + 7602176);   //   131,072 B
  float* bias0 = (float*)(ws + 7733248);   //     8,192 B
  float* bias1 = (float*)(ws + 7741440);   //     8,192 B
  short* zb0   = (short*)(ws + 7749632);   //   524,288 B
  short* zb1   = (short*)(ws + 8273920);   //   524,288 B
  short* h0b0  = (short*)(ws + 8798208);   // 1,048,576 B
  short* h0b1  = (short*)(ws + 9846784);
  short* h1b0  = (short*)(ws + 10895360);
  short* h1b1  = (short*)(ws + 11943936);
  int*   flags = (int*)  (ws + 12992512);  //     8,192 B (total ~13 MB)

  prep_kernel<<<20248, 256, 0, stream>>>(z0, h0in, Wih0, Whh0, bih0, bhh0,
                                         Wih1, Whh1, bih1, bhh1, fcW, linW,
                                         wsw0, wsw1, fcWsw, linWsw, bias0, bias1,
                                         zb1, h0b0, h1b0, flags);

  decoder_persist<<<512, 256, 0, stream>>>(
      wsw0, wsw1, fcWsw, linWsw, bias0, bias1, fcb, linb, c0in,
      h0b0, h0b1, h1b0, h1b1, zb0, zb1, flags, out);
}

// Round 3
// 8029.608 us; speedup vs baseline: 1.1124x; 1.1124x over previous
//
#include <hip/hip_runtime.h>

// Decoder: 2-layer LSTM, B=1024, IN=256, H=512, OUT=256, T2=128 (hardcoded).
// PERSISTENT kernel, 512 blocks x 256 thr, 2 blocks/CU (66KB LDS each).
// Round-6: BARRIER-FREE dataflow. 32 batch-groups of 32 rows, 16 j-blocks
// each, XCD-LOCAL (4 groups per XCD).
//   - All group barriers replaced by producer ready-counters per activation
//     buffer parity (z/h0/h1 x 2). A block waits only for the buffers it is
//     about to READ; blocks skew freely; WAR safety proven by the dependency
//     cycle (z->h0->h1->z) with 2-deep buffers.
//   - B-weight tiles double-buffered in REGISTERS: tau+1's 8 loads issue
//     before tau's MFMAs -> a full tau of latency hiding (breaks the
//     load->MFMA lockstep chain that made each tau cost a full L2 latency).
//   - activations exchanged through the XCD's own L2: plain stores + plain
//     loads; freshness via per-CU buffer_inv (L1-only) after each wait.
//   - weights pre-swizzled to MFMA B-frag order; fc/lin slice (+1 cell1
//     B-tile for j>=8) parked in LDS; c-state in VGPRs.

typedef __attribute__((ext_vector_type(8))) __bf16 bf16x8;
typedef __attribute__((ext_vector_type(16))) float f32x16;
typedef unsigned long long ull;

__device__ __forceinline__ f32x16 mfma_bf16(bf16x8 a, bf16x8 b, f32x16 c) {
  return __builtin_amdgcn_mfma_f32_32x32x16_bf16(a, b, c, 0, 0, 0);
}

__device__ __forceinline__ short f2bf(float f) {  // RNE fp32->bf16
  unsigned u = __float_as_uint(f);
  u += 0x7fffu + ((u >> 16) & 1u);
  return (short)(u >> 16);
}

__device__ __forceinline__ float sigm(float x) { return 1.0f / (1.0f + __expf(-x)); }
__device__ __forceinline__ float tanh_fast(float x) { return 2.0f / (1.0f + __expf(-2.0f * x)) - 1.0f; }

__device__ __forceinline__ f32x16 zero16() {
  f32x16 z;
#pragma unroll
  for (int i = 0; i < 16; ++i) z[i] = 0.0f;
  return z;
}

// A-tile LDS layout: row m (0..31) at stride 132 shorts.
#define AT_STRIDE 132
#define AT_WORDS (32 * AT_STRIDE)  // 4224 shorts = 8448 B per tile

// ---------------------------------------------------------------------------
// prep: swizzle weights into MFMA B-frag order; sum biases; init bf16 states;
// init ready-counters: cnt[z1]=8, cnt[h0_0]=16, cnt[h1_0]=16 (prep acts as
// the t=-1 producer of those parities); everything else zero.
// flags layout: per group g (32 groups): flags[g*256 + type*32],
// type: 0=z[0],1=z[1],2=h0[0],3=h0[1],4=h1[0],5=h1[1]. XCD ctrs at 8192+x*32.
// ---------------------------------------------------------------------------
__global__ __launch_bounds__(256) void prep_kernel(
    const float* __restrict__ z0, const float* __restrict__ h0in,
    const float* __restrict__ Wih0, const float* __restrict__ Whh0,
    const float* __restrict__ bih0, const float* __restrict__ bhh0,
    const float* __restrict__ Wih1, const float* __restrict__ Whh1,
    const float* __restrict__ bih1, const float* __restrict__ bhh1,
    const float* __restrict__ fcW, const float* __restrict__ linW,
    short* __restrict__ wsw0, short* __restrict__ wsw1,
    short* __restrict__ fcWsw, short* __restrict__ linWsw,
    float* __restrict__ bias0, float* __restrict__ bias1,
    short* __restrict__ zb1, short* __restrict__ h0b0, short* __restrict__ h1b0,
    int* __restrict__ flags)
{
  int idx = blockIdx.x * 256 + threadIdx.x;
  if (idx < 1572864) {  // wsw0 [j16][s48][g4][l64][8]; K=768 = [z 256 | h0 512]
    int jj = idx & 7, l = (idx >> 3) & 63, gg = (idx >> 9) & 3;
    int rest = idx >> 11;           // j*48 + s
    int s = rest % 48, b = rest / 48;
    int row = gg * 512 + b * 32 + (l & 31);
    int k = s * 16 + (l >> 5) * 8 + jj;
    wsw0[idx] = f2bf(k < 256 ? Wih0[row * 256 + k] : Whh0[row * 512 + (k - 256)]);
    return;
  }
  idx -= 1572864;
  if (idx < 2097152) {  // wsw1 [j16][s64][g4][l64][8]; K=1024 = [h0 512 | h1 512]
    int jj = idx & 7, l = (idx >> 3) & 63, gg = (idx >> 9) & 3;
    int rest = idx >> 11;           // j*64 + s
    int s = rest & 63, b = rest >> 6;
    int row = gg * 512 + b * 32 + (l & 31);
    int k = s * 16 + (l >> 5) * 8 + jj;
    wsw1[idx] = f2bf(k < 512 ? Wih1[row * 512 + k] : Whh1[row * 512 + (k - 512)]);
    return;
  }
  idx -= 2097152;
  if (idx < 131072) {  // fcWsw [jz8][s32][l64][8]
    int jj = idx & 7, l = (idx >> 3) & 63, s = (idx >> 9) & 31, jz = idx >> 14;
    int col = jz * 32 + (l & 31);
    int k = s * 16 + (l >> 5) * 8 + jj;
    fcWsw[idx] = f2bf(fcW[col * 512 + k]);
    return;
  }
  idx -= 131072;
  if (idx < 65536) {  // linWsw [jo8][s16][l64][8]
    int jj = idx & 7, l = (idx >> 3) & 63, s = (idx >> 9) & 15, jo = idx >> 13;
    int col = jo * 32 + (l & 31);
    int k = s * 16 + (l >> 5) * 8 + jj;
    linWsw[idx] = f2bf(linW[col * 256 + k]);
    return;
  }
  idx -= 65536;
  if (idx < 2048) { bias0[idx] = bih0[idx] + bhh0[idx]; return; }
  idx -= 2048;
  if (idx < 2048) { bias1[idx] = bih1[idx] + bhh1[idx]; return; }
  idx -= 2048;
  if (idx < 262144) { zb1[idx] = f2bf(z0[idx]); return; }
  idx -= 262144;
  if (idx < 524288) { h0b0[idx] = f2bf(h0in[idx]); return; }
  idx -= 524288;
  if (idx < 524288) { h1b0[idx] = f2bf(h0in[524288 + idx]); return; }
  idx -= 524288;
  if (idx < 8448) {  // ready-counters + xcd ctrs
    int v = 0;
    if (idx < 8192) {
      int off = idx & 255;
      if (off == 32) v = 8;                       // cnt_z[1] (prep wrote zb1)
      else if (off == 64 || off == 128) v = 16;   // cnt_h0[0], cnt_h1[0]
    }
    flags[idx] = v;
    return;
  }
}

// ---------------------------------------------------------------------------
// Dataflow sync primitives. Producers add 1 (after vmcnt drain) to the
// buffer-parity counter; consumers poll to a monotone target, then
// buffer_inv (per-CU L1 invalidate; the XCD L2 holding the data stays warm).
// ---------------------------------------------------------------------------
__device__ __forceinline__ void wait1(int* c0, int v0) {
  __syncthreads();
  if (threadIdx.x == 0) {
    while (__hip_atomic_load(c0, __ATOMIC_RELAXED, __HIP_MEMORY_SCOPE_AGENT) < v0)
      __builtin_amdgcn_s_sleep(2);
    asm volatile("buffer_inv" ::: "memory");
  }
  __syncthreads();
}

__device__ __forceinline__ void wait2(int* c0, int v0, int* c1, int v1) {
  __syncthreads();
  if (threadIdx.x == 0) {
    while (__hip_atomic_load(c0, __ATOMIC_RELAXED, __HIP_MEMORY_SCOPE_AGENT) < v0 ||
           __hip_atomic_load(c1, __ATOMIC_RELAXED, __HIP_MEMORY_SCOPE_AGENT) < v1)
      __builtin_amdgcn_s_sleep(2);
    asm volatile("buffer_inv" ::: "memory");
  }
  __syncthreads();
}

__device__ __forceinline__ void produce(int* c) {
  asm volatile("s_waitcnt vmcnt(0)" ::: "memory");
  __syncthreads();
  if (threadIdx.x == 0)
    __hip_atomic_fetch_add(c, 1, __ATOMIC_RELAXED, __HIP_MEMORY_SCOPE_AGENT);
}

// ---------------------------------------------------------------------------
// LSTM cell phase (M=32): gates = [A|B panels] @ W^T + bias; c in regs;
// h -> plain store (same-XCD L2). B-weight tiles double-buffered in REGS:
// tau+1's loads issue before tau's MFMAs. First NLDS B-tiles from LDS cache.
// ---------------------------------------------------------------------------
template <int NT, int TA, int NLDS>
__device__ __forceinline__ void cell_phase(
    short* At0, short* At1, float* gbuf,
    const short* __restrict__ srcA, int ldA,
    const short* __restrict__ srcB, int ldB,
    const short* wlds, const short* __restrict__ wglob,
    const float* __restrict__ bias,
    float* cr, short* hout, int row0, int j0)
{
  const int t = threadIdx.x;          // 0..255, 4 waves
  const int gq = t >> 6, l = t & 63;  // wave = gate quadrant
  const int ln = l & 31, kh = l >> 5;
  const int sks = t & 15, sm = t >> 4;   // staging: ks 0..15, m 0..15 (+16)
  short* Abuf[2] = {At0, At1};
  f32x16 acc = zero16();
  uint4 preA[2];
  uint4 bA[8], bB[8];

  // stage A(0) + issue B(0) loads (B(0) overlaps the LDS write + sync)
#pragma unroll
  for (int i = 0; i < 2; ++i)
    preA[i] = *(const uint4*)&srcA[(row0 + sm + 16 * i) * ldA + sks * 8];
  {
    const short* bt = (0 < NLDS) ? wlds : wglob;
#pragma unroll
    for (int s = 0; s < 8; ++s)
      bA[s] = *(const uint4*)&bt[((s * 4 + gq) * 64 + l) * 8];
  }
#pragma unroll
  for (int i = 0; i < 2; ++i)
    *(uint4*)&Abuf[0][(sm + 16 * i) * AT_STRIDE + sks * 8] = preA[i];
  __syncthreads();

#pragma unroll
  for (int tau = 0; tau < NT; ++tau) {
    uint4* bcur = (tau & 1) ? bB : bA;   // static under full unroll
    uint4* bnxt = (tau & 1) ? bA : bB;
    if (tau + 1 < NT) {
      const short* src; int ld, col;
      if (tau + 1 < TA) { src = srcA; ld = ldA; col = (tau + 1) * 128; }
      else              { src = srcB; ld = ldB; col = (tau + 1 - TA) * 128; }
#pragma unroll
      for (int i = 0; i < 2; ++i)
        preA[i] = *(const uint4*)&src[(row0 + sm + 16 * i) * ld + col + sks * 8];
      const short* bt = ((tau + 1 < NLDS) ? wlds : wglob) + (tau + 1) * 16384;
#pragma unroll
      for (int s = 0; s < 8; ++s)
        bnxt[s] = *(const uint4*)&bt[((s * 4 + gq) * 64 + l) * 8];
    }
    const short* at = Abuf[tau & 1];
#pragma unroll
    for (int s = 0; s < 8; ++s) {
      bf16x8 a = *(const bf16x8*)&at[ln * AT_STRIDE + (s * 2 + kh) * 8];
      bf16x8 b;
      __builtin_memcpy(&b, &bcur[s], 16);
      acc = mfma_bf16(a, b, acc);
    }
    if (tau + 1 < NT) {
      short* nxt = Abuf[(tau + 1) & 1];
#pragma unroll
      for (int i = 0; i < 2; ++i)
        *(uint4*)&nxt[(sm + 16 * i) * AT_STRIDE + sks * 8] = preA[i];
    }
    __syncthreads();
  }
  // C layout: col = lane&31, row = (r&3)+8*(r>>2)+4*(lane>>5). gbuf aliases At.
#pragma unroll
  for (int r = 0; r < 16; ++r) {
    int mloc = (r & 3) + 8 * (r >> 2) + 4 * kh;
    gbuf[(gq * 32 + mloc) * 32 + ln] = acc[r];
  }
  __syncthreads();
  const int m = t >> 3, nb = (t & 7) * 4;  // m 0..31, nb 0..28
  short hh[4];
#pragma unroll
  for (int u = 0; u < 4; ++u) {
    int n = nb + u, jn = j0 + n;
    float gi = gbuf[(0 * 32 + m) * 32 + n] + bias[jn];
    float gf = gbuf[(1 * 32 + m) * 32 + n] + bias[512 + jn];
    float gg = gbuf[(2 * 32 + m) * 32 + n] + bias[1024 + jn];
    float go = gbuf[(3 * 32 + m) * 32 + n] + bias[1536 + jn];
    float cn = sigm(gf) * cr[u] + sigm(gi) * tanh_fast(gg);
    cr[u] = cn;
    hh[u] = f2bf(sigm(go) * tanh_fast(cn));
  }
  ull hv; __builtin_memcpy(&hv, hh, 8);
  *(ull*)&hout[(size_t)(row0 + m) * 512 + j0 + nb] = hv;  // plain: same-XCD L2
}

// ---------------------------------------------------------------------------
// Projection partials (fc or lin): B entirely from LDS cache. Waves = kq
// (K-partial); 4 K-partials land in gbuf[kq][m][n] for combine.
// ---------------------------------------------------------------------------
template <int NQ>
__device__ __forceinline__ void proj_partials(
    short* At0, float* gbuf,
    const short* __restrict__ src, int ld,
    const short* wblk, int row0)
{
  const int t = threadIdx.x;
  const int kq = t >> 6, l = t & 63;
  const int ln = l & 31, kh = l >> 5;
  const int sks = t & 15, sm = t >> 4;
  f32x16 acc = zero16();
#pragma unroll
  for (int q = 0; q < NQ; ++q) {
    __syncthreads();
    uint4 pre[2];
#pragma unroll
    for (int i = 0; i < 2; ++i)
      pre[i] = *(const uint4*)&src[(row0 + sm + 16 * i) * ld + q * 128 + sks * 8];
#pragma unroll
    for (int i = 0; i < 2; ++i)
      *(uint4*)&At0[(sm + 16 * i) * AT_STRIDE + sks * 8] = pre[i];
    __syncthreads();
#pragma unroll
    for (int sl = 0; sl < 2; ++sl) {
      int s16 = kq * 2 + sl;
      bf16x8 a = *(const bf16x8*)&At0[ln * AT_STRIDE + (s16 * 2 + kh) * 8];
      bf16x8 b = *(const bf16x8*)&wblk[((q * 8 + s16) * 64 + l) * 8];
      acc = mfma_bf16(a, b, acc);
    }
  }
  __syncthreads();
#pragma unroll
  for (int r = 0; r < 16; ++r) {
    int mloc = (r & 3) + 8 * (r >> 2) + 4 * kh;
    gbuf[(kq * 32 + mloc) * 32 + ln] = acc[r];
  }
  __syncthreads();
}

__global__ __launch_bounds__(256, 2) void decoder_persist(
    const short* __restrict__ wsw0, const short* __restrict__ wsw1,
    const short* __restrict__ fcWsw, const short* __restrict__ linWsw,
    const float* __restrict__ bias0, const float* __restrict__ bias1,
    const float* __restrict__ fcb, const float* __restrict__ linb,
    const float* __restrict__ c0in,
    short* h0x, short* h0y, short* h1x, short* h1y, short* zx, short* zy,
    int* flags, float* __restrict__ outp)
{
  __shared__ __align__(16) char arena[2 * AT_WORDS * 2];  // 16896 B (A dbuf / gbuf)
  __shared__ __align__(16) short wc[24576];               // 49152 B weight cache
  __shared__ int sgj[2];
  short* At0 = (short*)arena;
  short* At1 = At0 + AT_WORDS;
  float* gbuf = (float*)arena;   // 16384 B, aliases the A tiles

  // --- self-assignment: physical XCD id -> (group, j) slot ---
  if (threadIdx.x == 0) {
    unsigned xcc;
    asm volatile("s_getreg_b32 %0, hwreg(HW_REG_XCC_ID, 0, 32)" : "=s"(xcc));
    xcc &= 7u;
    int slot = __hip_atomic_fetch_add(&flags[8192 + (int)xcc * 32], 1,
                                      __ATOMIC_RELAXED, __HIP_MEMORY_SCOPE_AGENT);
    slot &= 63;                           // hardening: wrong-answer > hang
    sgj[0] = (int)xcc * 4 + (slot >> 4);  // group: 4 per XCD
    sgj[1] = slot & 15;                   // j-tile within group
  }
  __syncthreads();
  const int g = sgj[0], j = sgj[1];
  const int row0 = g * 32, j0 = j * 32;
  int* cnt = &flags[g * 256];             // 6 counters, one cacheline each
#define CZ(i)  (cnt + (0 + (i)) * 32)
#define CH0(i) (cnt + (2 + (i)) * 32)
#define CH1(i) (cnt + (4 + (i)) * 32)

  // --- park fc/lin slice (+1 cell1 B-tile for j>=8) in LDS, loaded once ---
  if (j < 8) {
    const short* s1 = fcWsw + j * 16384;
    for (int i = threadIdx.x; i < 2048; i += 256)
      *(uint4*)&wc[i * 8] = *(const uint4*)&s1[i * 8];
  } else {
    const short* s1 = linWsw + (j - 8) * 8192;
    for (int i = threadIdx.x; i < 1024; i += 256)
      *(uint4*)&wc[i * 8] = *(const uint4*)&s1[i * 8];
    const short* s2 = wsw1 + j * 131072;
    for (int i = threadIdx.x; i < 2048; i += 256)   // 1 tile
      *(uint4*)&wc[8192 + i * 8] = *(const uint4*)&s2[i * 8];
  }
  const short* wl1 = wc + 8192;  // valid only for j>=8 (NLDS=1)
  __syncthreads();

  // --- c-state in registers for the whole run ---
  float c0r[4], c1r[4];
  {
    const int m = threadIdx.x >> 3, nb = (threadIdx.x & 7) * 4;
#pragma unroll
    for (int u = 0; u < 4; ++u) {
      c0r[u] = c0in[(size_t)(row0 + m) * 512 + j0 + nb + u];
      c1r[u] = c0in[524288 + (size_t)(row0 + m) * 512 + j0 + nb + u];
    }
  }

  short* h0buf[2] = {h0x, h0y};
  short* h1buf[2] = {h1x, h1y};
  short* zbuf[2] = {zx, zy};
  const short* wg0 = wsw0 + j * 98304;
  const short* wg1 = wsw1 + j * 131072;

#pragma unroll 1
  for (int t = 0; t < 128; ++t) {
    const int p = t & 1;
    const int half = (t >> 1) + 1;        // # completed write-rounds of t-1 parity
    const int full = (t + 3) >> 1;        // # completed write-rounds incl. this step
    // P1: cell0  (K = [z 256 | h0 512]); reads z(t-1), h0(t-1)
    wait2(CZ(p ^ 1), 8 * half, CH0(p), 16 * half);
    cell_phase<6, 2, 0>(At0, At1, gbuf, zbuf[p ^ 1], 256, h0buf[p], 512,
                        nullptr, wg0, bias0, c0r, h0buf[p ^ 1], row0, j0);
    produce(CH0(p ^ 1));
    // P2: cell1  (K = [h0(t) 512 | h1(t-1) 512]); j>=8: first B-tile from LDS
    wait2(CH0(p ^ 1), 16 * full, CH1(p), 16 * half);
    if (j < 8)
      cell_phase<8, 4, 0>(At0, At1, gbuf, h0buf[p ^ 1], 512, h1buf[p], 512,
                          wl1, wg1, bias1, c1r, h1buf[p ^ 1], row0, j0);
    else
      cell_phase<8, 4, 1>(At0, At1, gbuf, h0buf[p ^ 1], 512, h1buf[p], 512,
                          wl1, wg1, bias1, c1r, h1buf[p ^ 1], row0, j0);
    produce(CH1(p ^ 1));
    // P3: j<8 -> z(t) = fc(h1(t)); j>=8 -> out(t-1) = lin(z(t-1))
    if (j < 8) {
      wait1(CH1(p ^ 1), 16 * full);
      proj_partials<4>(At0, gbuf, h1buf[p ^ 1], 512, wc, row0);
      const int m = threadIdx.x >> 3, nb = (threadIdx.x & 7) * 4;
      const int n0 = j * 32;
      short zz[4];
#pragma unroll
      for (int u = 0; u < 4; ++u) {
        int n = nb + u;
        float v = gbuf[(0 * 32 + m) * 32 + n] + gbuf[(1 * 32 + m) * 32 + n] +
                  gbuf[(2 * 32 + m) * 32 + n] + gbuf[(3 * 32 + m) * 32 + n] +
                  fcb[n0 + n];
        zz[u] = f2bf(v);
      }
      ull zv; __builtin_memcpy(&zv, zz, 8);
      *(ull*)&zbuf[p][(size_t)(row0 + m) * 256 + n0 + nb] = zv;
      produce(CZ(p));
    } else if (t > 0) {
      // z(t-1) freshness guaranteed by this step's P1 wait (program order)
      proj_partials<2>(At0, gbuf, zbuf[p ^ 1], 256, wc, row0);
      const int m = threadIdx.x >> 3, nb = (threadIdx.x & 7) * 4;
      const int n0 = (j - 8) * 32;
      float4 ov;
      float* po = &ov.x;
#pragma unroll
      for (int u = 0; u < 4; ++u) {
        int n = nb + u;
        po[u] = gbuf[(0 * 32 + m) * 32 + n] + gbuf[(1 * 32 + m) * 32 + n] +
                gbuf[(2 * 32 + m) * 32 + n] + gbuf[(3 * 32 + m) * 32 + n] +
                linb[n0 + n];
      }
      *(float4*)&outp[(size_t)(t - 1) * 262144 + (size_t)(row0 + m) * 256 + n0 + nb] = ov;
    }
  }
  // final out(127) from z(127) in zbuf[1]: z[1] rounds = prep + fc(1..127 odd) = 65
  if (j >= 8) {
    wait1(CZ(1), 8 * 65);
    proj_partials<2>(At0, gbuf, zbuf[1], 256, wc, row0);
    const int m = threadIdx.x >> 3, nb = (threadIdx.x & 7) * 4;
    const int n0 = (j - 8) * 32;
    float4 ov;
    float* po = &ov.x;
#pragma unroll
    for (int u = 0; u < 4; ++u) {
      int n = nb + u;
      po[u] = gbuf[(0 * 32 + m) * 32 + n] + gbuf[(1 * 32 + m) * 32 + n] +
              gbuf[(2 * 32 + m) * 32 + n] + gbuf[(3 * 32 + m) * 32 + n] +
              linb[n0 + n];
    }
    *(float4*)&outp[(size_t)127 * 262144 + (size_t)(row0 + m) * 256 + n0 + nb] = ov;
  }
#undef CZ
#undef CH0
#undef CH1
}

// ---------------------------------------------------------------------------
extern "C" void kernel_launch(void* const* d_in, const int* in_sizes, int n_in,
                              void* d_out, int out_size, void* d_ws, size_t ws_size,
                              hipStream_t stream) {
  const float* z0   = (const float*)d_in[0];
  const float* h0in = (const float*)d_in[1];
  const float* c0in = (const float*)d_in[2];
  const float* Wih0 = (const float*)d_in[3];
  const float* Whh0 = (const float*)d_in[4];
  const float* bih0 = (const float*)d_in[5];
  const float* bhh0 = (const float*)d_in[6];
  const float* Wih1 = (const float*)d_in[7];
  const float* Whh1 = (const float*)d_in[8];
  const float* bih1 = (const float*)d_in[9];
  const float* bhh1 = (const float*)d_in[10];
  const float* fcW  = (const float*)d_in[11];
  const float* fcb  = (const float*)d_in[12];
  const float* linW = (const float*)d_in[13];
  const float* linb = (const float*)d_in[14];
  float* out = (float*)d_out;

  char* ws = (char*)d_ws;
  short* wsw0  = (short*)(ws + 0);         // 3,145,728 B
  short* wsw1  = (short*)(ws + 3145728);   // 4,194,304 B
  short* fcWsw = (short*)(ws + 7340032);   //   262,144 B
  short* linWsw= (short*)(ws + 7602176);   //   131,072 B
  float* bias0 = (float*)(ws + 7733248);   //     8,192 B
  float* bias1 = (float*)(ws + 7741440);   //     8,192 B
  short* zb0   = (short*)(ws + 7749632);   //   524,288 B
  short* zb1   = (short*)(ws + 8273920);   //   524,288 B
  short* h0b0  = (short*)(ws + 8798208);   // 1,048,576 B
  short* h0b1  = (short*)(ws + 9846784);
  short* h1b0  = (short*)(ws + 10895360);
  short* h1b1  = (short*)(ws + 11943936);
  int*   flags = (int*)  (ws + 12992512);  //    33,792 B (total ~13 MB)

  prep_kernel<<<20273, 256, 0, stream>>>(z0, h0in, Wih0, Whh0, bih0, bhh0,
                                         Wih1, Whh1, bih1, bhh1, fcW, linW,
                                         wsw0, wsw1, fcWsw, linWsw, bias0, bias1,
                                         zb1, h0b0, h1b0, flags);

  decoder_persist<<<512, 256, 0, stream>>>(
      wsw0, wsw1, fcWsw, linWsw, bias0, bias1, fcb, linb, c0in,
      h0b0, h0b1, h1b0, h1b1, zb0, zb1, flags, out);
}

// Round 4
// 6413.467 us; speedup vs baseline: 1.3927x; 1.2520x over previous
//
#include <hip/hip_runtime.h>

// Decoder: 2-layer LSTM, B=1024, IN=256, H=512, OUT=256, T2=128 (hardcoded).
// PERSISTENT kernel, 512 blocks x 256 thr, 2 blocks/CU (~57KB LDS each).
// Round-7: DMA-pipelined cells. 32 batch-groups of 32 rows, 16 j-blocks each,
// XCD-LOCAL (4 groups per XCD), barrier-free dataflow handshakes (r6 scheme).
// NEW: cell phases stream A (activations) and B (weights) via
// __builtin_amdgcn_global_load_lds in K=64 granules: B 3-deep, A 2-deep,
// raw s_barrier + counted s_waitcnt vmcnt(9/5/0) — loads stay in flight
// across barriers; the compiler cannot sink or drain this pipeline (the
// r5/r6 VGPR-prefetch was silently sunk by the compiler -> lockstep
// load->MFMA chains of one L2/L3 latency per K-tile, the 8ms invariant).
//   - A is K-major in LDS (per-lane gather on the DMA global side) ->
//     conflict-free ds_reads, no swizzle, producers unchanged.
//   - weights pre-swizzled to MFMA B-frag order (granule-contiguous 16KB).
//   - c-state in VGPRs; activations through XCD-local L2 (plain st/ld +
//     buffer_inv at handshakes); fc/lin proj streams B direct from L2.

typedef __attribute__((ext_vector_type(8))) __bf16 bf16x8;
typedef __attribute__((ext_vector_type(16))) float f32x16;
typedef unsigned long long ull;

__device__ __forceinline__ f32x16 mfma_bf16(bf16x8 a, bf16x8 b, f32x16 c) {
  return __builtin_amdgcn_mfma_f32_32x32x16_bf16(a, b, c, 0, 0, 0);
}

__device__ __forceinline__ short f2bf(float f) {  // RNE fp32->bf16
  unsigned u = __float_as_uint(f);
  u += 0x7fffu + ((u >> 16) & 1u);
  return (short)(u >> 16);
}

__device__ __forceinline__ float sigm(float x) { return 1.0f / (1.0f + __expf(-x)); }
__device__ __forceinline__ float tanh_fast(float x) { return 2.0f / (1.0f + __expf(-2.0f * x)) - 1.0f; }

__device__ __forceinline__ f32x16 zero16() {
  f32x16 z;
#pragma unroll
  for (int i = 0; i < 16; ++i) z[i] = 0.0f;
  return z;
}

__device__ __forceinline__ void dma16(const void* g, void* l) {
  __builtin_amdgcn_global_load_lds(
      (const __attribute__((address_space(1))) void*)g,
      (__attribute__((address_space(3))) void*)l, 16, 0, 0);
}

// proj A-tile LDS layout: row m (0..31) at stride 132 shorts (padded).
#define AT_STRIDE 132

// ---------------------------------------------------------------------------
// prep: swizzle weights into MFMA B-frag order (granule-contiguous); sum
// biases; init bf16 states; init ready-counters (cnt[z1]=8, cnt[h0_0]=16,
// cnt[h1_0]=16 — prep is the t=-1 producer); zero the rest + XCD ctrs.
// flags: per group g: flags[g*256 + type*32], type 0=z[0],1=z[1],2=h0[0],
// 3=h0[1],4=h1[0],5=h1[1]. XCD ctrs at 8192+x*32.
// ---------------------------------------------------------------------------
__global__ __launch_bounds__(256) void prep_kernel(
    const float* __restrict__ z0, const float* __restrict__ h0in,
    const float* __restrict__ Wih0, const float* __restrict__ Whh0,
    const float* __restrict__ bih0, const float* __restrict__ bhh0,
    const float* __restrict__ Wih1, const float* __restrict__ Whh1,
    const float* __restrict__ bih1, const float* __restrict__ bhh1,
    const float* __restrict__ fcW, const float* __restrict__ linW,
    short* __restrict__ wsw0, short* __restrict__ wsw1,
    short* __restrict__ fcWsw, short* __restrict__ linWsw,
    float* __restrict__ bias0, float* __restrict__ bias1,
    short* __restrict__ zb1, short* __restrict__ h0b0, short* __restrict__ h1b0,
    int* __restrict__ flags)
{
  int idx = blockIdx.x * 256 + threadIdx.x;
  if (idx < 1572864) {  // wsw0 [j16][s48][g4][l64][8]; K=768 = [z 256 | h0 512]
    int jj = idx & 7, l = (idx >> 3) & 63, gg = (idx >> 9) & 3;
    int rest = idx >> 11;           // j*48 + s
    int s = rest % 48, b = rest / 48;
    int row = gg * 512 + b * 32 + (l & 31);
    int k = s * 16 + (l >> 5) * 8 + jj;
    wsw0[idx] = f2bf(k < 256 ? Wih0[row * 256 + k] : Whh0[row * 512 + (k - 256)]);
    return;
  }
  idx -= 1572864;
  if (idx < 2097152) {  // wsw1 [j16][s64][g4][l64][8]; K=1024 = [h0 512 | h1 512]
    int jj = idx & 7, l = (idx >> 3) & 63, gg = (idx >> 9) & 3;
    int rest = idx >> 11;           // j*64 + s
    int s = rest & 63, b = rest >> 6;
    int row = gg * 512 + b * 32 + (l & 31);
    int k = s * 16 + (l >> 5) * 8 + jj;
    wsw1[idx] = f2bf(k < 512 ? Wih1[row * 512 + k] : Whh1[row * 512 + (k - 512)]);
    return;
  }
  idx -= 2097152;
  if (idx < 131072) {  // fcWsw [jz8][s32][l64][8]
    int jj = idx & 7, l = (idx >> 3) & 63, s = (idx >> 9) & 31, jz = idx >> 14;
    int col = jz * 32 + (l & 31);
    int k = s * 16 + (l >> 5) * 8 + jj;
    fcWsw[idx] = f2bf(fcW[col * 512 + k]);
    return;
  }
  idx -= 131072;
  if (idx < 65536) {  // linWsw [jo8][s16][l64][8]
    int jj = idx & 7, l = (idx >> 3) & 63, s = (idx >> 9) & 15, jo = idx >> 13;
    int col = jo * 32 + (l & 31);
    int k = s * 16 + (l >> 5) * 8 + jj;
    linWsw[idx] = f2bf(linW[col * 256 + k]);
    return;
  }
  idx -= 65536;
  if (idx < 2048) { bias0[idx] = bih0[idx] + bhh0[idx]; return; }
  idx -= 2048;
  if (idx < 2048) { bias1[idx] = bih1[idx] + bhh1[idx]; return; }
  idx -= 2048;
  if (idx < 262144) { zb1[idx] = f2bf(z0[idx]); return; }
  idx -= 262144;
  if (idx < 524288) { h0b0[idx] = f2bf(h0in[idx]); return; }
  idx -= 524288;
  if (idx < 524288) { h1b0[idx] = f2bf(h0in[524288 + idx]); return; }
  idx -= 524288;
  if (idx < 8448) {  // ready-counters + xcd ctrs
    int v = 0;
    if (idx < 8192) {
      int off = idx & 255;
      if (off == 32) v = 8;                       // cnt_z[1] (prep wrote zb1)
      else if (off == 64 || off == 128) v = 16;   // cnt_h0[0], cnt_h1[0]
    }
    flags[idx] = v;
    return;
  }
}

// ---------------------------------------------------------------------------
// Dataflow sync: producers add 1 (after vmcnt drain); consumers poll to a
// monotone target, then buffer_inv (per-CU L1 invalidate; XCD L2 stays warm).
// ---------------------------------------------------------------------------
__device__ __forceinline__ void wait1(int* c0, int v0) {
  __syncthreads();
  if (threadIdx.x == 0) {
    while (__hip_atomic_load(c0, __ATOMIC_RELAXED, __HIP_MEMORY_SCOPE_AGENT) < v0)
      __builtin_amdgcn_s_sleep(2);
    asm volatile("buffer_inv" ::: "memory");
  }
  __syncthreads();
}

__device__ __forceinline__ void wait2(int* c0, int v0, int* c1, int v1) {
  __syncthreads();
  if (threadIdx.x == 0) {
    while (__hip_atomic_load(c0, __ATOMIC_RELAXED, __HIP_MEMORY_SCOPE_AGENT) < v0 ||
           __hip_atomic_load(c1, __ATOMIC_RELAXED, __HIP_MEMORY_SCOPE_AGENT) < v1)
      __builtin_amdgcn_s_sleep(2);
    asm volatile("buffer_inv" ::: "memory");
  }
  __syncthreads();
}

__device__ __forceinline__ void produce(int* c) {
  asm volatile("s_waitcnt vmcnt(0)" ::: "memory");
  __syncthreads();
  if (threadIdx.x == 0)
    __hip_atomic_fetch_add(c, 1, __ATOMIC_RELAXED, __HIP_MEMORY_SCOPE_AGENT);
}

// ---------------------------------------------------------------------------
// DMA-pipelined LSTM cell phase (M=32, K granule = 64).
//   A LDS (K-major, per granule 4KB): slot ((u*2+kh)*32+ln)*8 shorts,
//     2 buffers. B LDS: granule 16KB = [u4][gate4][l64][8 shorts], 3 buffers.
//   Issue order per granule: A(g+2) [1 instr], B(g+3) [4 instrs].
//   Steady outstanding before compute(g): B(g+1)4 + A(g+1)1 + B(g+2)4 = 9.
// ---------------------------------------------------------------------------
template <int NG, int TAG>
__device__ __forceinline__ void cell_phase_dma(
    short* Al, short* Bl, float* gbuf,
    const short* __restrict__ srcA, int ldA,
    const short* __restrict__ srcB, int ldB,
    const short* __restrict__ wgl,
    const float* __restrict__ bias,
    float* cr, short* hout, int row0, int j0)
{
  const int t = threadIdx.x;          // 0..255, 4 waves
  const int w = t >> 6, l = t & 63;
  const int gq = w;                   // wave = gate quadrant
  const int ln = l & 31, kh = l >> 5;

  auto issueA = [&](int g) {
    const short* asrc; int ald, gk;
    if (g < TAG) { asrc = srcA; ald = ldA; gk = g * 64; }
    else         { asrc = srcB; ald = ldB; gk = (g - TAG) * 64; }
    const short* gp = asrc + (size_t)(row0 + ln) * ald + gk + w * 16 + kh * 8;
    dma16(gp, Al + (g & 1) * 2048 + w * 512);
  };
  auto issueB = [&](int g) {
    const short* gb = wgl + (size_t)g * 8192;
    short* lb = Bl + (g % 3) * 8192;
#pragma unroll
    for (int i = 0; i < 4; ++i)
      dma16(gb + (i * 256 + w * 64 + l) * 8, lb + i * 2048 + w * 512);
  };

  f32x16 acc = zero16();
  // prologue queue (oldest->newest): A0 B0(4) A1 B1(4) B2(4) = 14 instrs
  issueA(0); issueB(0);
  issueA(1); issueB(1);
  issueB(2);

#pragma unroll
  for (int g = 0; g < NG; ++g) {
    if (g + 2 < NG)      asm volatile("s_waitcnt vmcnt(9)" ::: "memory");
    else if (g + 1 < NG) asm volatile("s_waitcnt vmcnt(5)" ::: "memory");
    else                 asm volatile("s_waitcnt vmcnt(0)" ::: "memory");
    __builtin_amdgcn_s_barrier();          // granule g fully in LDS (all waves)
    __builtin_amdgcn_sched_barrier(0);
    const short* al = Al + (g & 1) * 2048;
    const short* bl = Bl + (g % 3) * 8192;
#pragma unroll
    for (int u = 0; u < 4; ++u) {
      bf16x8 a = *(const bf16x8*)&al[((u * 2 + kh) * 32 + ln) * 8];
      bf16x8 b = *(const bf16x8*)&bl[((u * 4 + gq) * 64 + l) * 8];
      acc = mfma_bf16(a, b, acc);
    }
    __builtin_amdgcn_sched_barrier(0);
    __builtin_amdgcn_s_barrier();          // all waves done reading granule g
    __builtin_amdgcn_sched_barrier(0);
    if (g + 2 < NG) issueA(g + 2);         // overwrites A buf read this iter
    if (g + 3 < NG) issueB(g + 3);         // overwrites B buf read this iter
  }

  // C layout: col = lane&31, row = (r&3)+8*(r>>2)+4*(lane>>5).
  // gbuf aliases the B buffers (pipeline drained: vmcnt(0) at g=NG-1).
#pragma unroll
  for (int r = 0; r < 16; ++r) {
    int mloc = (r & 3) + 8 * (r >> 2) + 4 * kh;
    gbuf[(gq * 32 + mloc) * 32 + ln] = acc[r];
  }
  __syncthreads();
  const int m = t >> 3, nb = (t & 7) * 4;  // m 0..31, nb 0..28
  short hh[4];
#pragma unroll
  for (int u = 0; u < 4; ++u) {
    int n = nb + u, jn = j0 + n;
    float gi = gbuf[(0 * 32 + m) * 32 + n] + bias[jn];
    float gf = gbuf[(1 * 32 + m) * 32 + n] + bias[512 + jn];
    float gg = gbuf[(2 * 32 + m) * 32 + n] + bias[1024 + jn];
    float go = gbuf[(3 * 32 + m) * 32 + n] + bias[1536 + jn];
    float cn = sigm(gf) * cr[u] + sigm(gi) * tanh_fast(gg);
    cr[u] = cn;
    hh[u] = f2bf(sigm(go) * tanh_fast(cn));
  }
  ull hv; __builtin_memcpy(&hv, hh, 8);
  *(ull*)&hout[(size_t)(row0 + m) * 512 + j0 + nb] = hv;  // plain: same-XCD L2
}

// ---------------------------------------------------------------------------
// Projection partials (fc or lin): B streamed from global (small, L2-hot).
// Waves = kq (K-partial); 4 K-partials land in gbuf[kq][m][n] for combine.
// Runs after the cell pipeline is fully drained; __syncthreads is safe here.
// ---------------------------------------------------------------------------
template <int NQ>
__device__ __forceinline__ void proj_partials(
    short* At0, float* gbuf,
    const short* __restrict__ src, int ld,
    const short* __restrict__ wblk, int row0)
{
  const int t = threadIdx.x;
  const int kq = t >> 6, l = t & 63;
  const int ln = l & 31, kh = l >> 5;
  const int sks = t & 15, sm = t >> 4;
  f32x16 acc = zero16();
#pragma unroll
  for (int q = 0; q < NQ; ++q) {
    __syncthreads();
    uint4 pre[2];
#pragma unroll
    for (int i = 0; i < 2; ++i)
      pre[i] = *(const uint4*)&src[(row0 + sm + 16 * i) * ld + q * 128 + sks * 8];
#pragma unroll
    for (int i = 0; i < 2; ++i)
      *(uint4*)&At0[(sm + 16 * i) * AT_STRIDE + sks * 8] = pre[i];
    __syncthreads();
#pragma unroll
    for (int sl = 0; sl < 2; ++sl) {
      int s16 = kq * 2 + sl;
      bf16x8 a = *(const bf16x8*)&At0[ln * AT_STRIDE + (s16 * 2 + kh) * 8];
      bf16x8 b = *(const bf16x8*)&wblk[((q * 8 + s16) * 64 + l) * 8];
      acc = mfma_bf16(a, b, acc);
    }
  }
  __syncthreads();
#pragma unroll
  for (int r = 0; r < 16; ++r) {
    int mloc = (r & 3) + 8 * (r >> 2) + 4 * kh;
    gbuf[(kq * 32 + mloc) * 32 + ln] = acc[r];
  }
  __syncthreads();
}

__global__ __launch_bounds__(256, 2) void decoder_persist(
    const short* __restrict__ wsw0, const short* __restrict__ wsw1,
    const short* __restrict__ fcWsw, const short* __restrict__ linWsw,
    const float* __restrict__ bias0, const float* __restrict__ bias1,
    const float* __restrict__ fcb, const float* __restrict__ linb,
    const float* __restrict__ c0in,
    short* h0x, short* h0y, short* h1x, short* h1y, short* zx, short* zy,
    int* flags, float* __restrict__ outp)
{
  __shared__ __align__(16) short Al[4096];    //  8 KB: A granules, 2 buffers
  __shared__ __align__(16) short Bl[24576];   // 48 KB: B granules, 3 buffers
  __shared__ int sgj[2];
  float* gbuf = (float*)(Bl + 4352);          // 16 KB, aliases B buffers
  short* Atp = Bl;                            // proj A-stage (8448 B, padded)

  // --- self-assignment: physical XCD id -> (group, j) slot ---
  if (threadIdx.x == 0) {
    unsigned xcc;
    asm volatile("s_getreg_b32 %0, hwreg(HW_REG_XCC_ID, 0, 32)" : "=s"(xcc));
    xcc &= 7u;
    int slot = __hip_atomic_fetch_add(&flags[8192 + (int)xcc * 32], 1,
                                      __ATOMIC_RELAXED, __HIP_MEMORY_SCOPE_AGENT);
    slot &= 63;                           // hardening: wrong-answer > hang
    sgj[0] = (int)xcc * 4 + (slot >> 4);  // group: 4 per XCD
    sgj[1] = slot & 15;                   // j-tile within group
  }
  __syncthreads();
  const int g = sgj[0], j = sgj[1];
  const int row0 = g * 32, j0 = j * 32;
  int* cnt = &flags[g * 256];             // 6 counters, one cacheline each
#define CZ(i)  (cnt + (0 + (i)) * 32)
#define CH0(i) (cnt + (2 + (i)) * 32)
#define CH1(i) (cnt + (4 + (i)) * 32)

  // --- c-state in registers for the whole run ---
  float c0r[4], c1r[4];
  {
    const int m = threadIdx.x >> 3, nb = (threadIdx.x & 7) * 4;
#pragma unroll
    for (int u = 0; u < 4; ++u) {
      c0r[u] = c0in[(size_t)(row0 + m) * 512 + j0 + nb + u];
      c1r[u] = c0in[524288 + (size_t)(row0 + m) * 512 + j0 + nb + u];
    }
  }

  short* h0buf[2] = {h0x, h0y};
  short* h1buf[2] = {h1x, h1y};
  short* zbuf[2] = {zx, zy};
  const short* wg0 = wsw0 + j * 98304;
  const short* wg1 = wsw1 + j * 131072;
  const short* wpj = (j < 8) ? (fcWsw + j * 16384) : (linWsw + (j - 8) * 8192);

#pragma unroll 1
  for (int t = 0; t < 128; ++t) {
    const int p = t & 1;
    const int half = (t >> 1) + 1;        // completed write-rounds, t-1 parity
    const int full = (t + 3) >> 1;        // incl. this step
    // P1: cell0  (K = [z 256 | h0 512]); reads z(t-1), h0(t-1)
    wait2(CZ(p ^ 1), 8 * half, CH0(p), 16 * half);
    cell_phase_dma<12, 4>(Al, Bl, gbuf, zbuf[p ^ 1], 256, h0buf[p], 512,
                          wg0, bias0, c0r, h0buf[p ^ 1], row0, j0);
    produce(CH0(p ^ 1));
    // P2: cell1  (K = [h0(t) 512 | h1(t-1) 512])
    wait2(CH0(p ^ 1), 16 * full, CH1(p), 16 * half);
    cell_phase_dma<16, 8>(Al, Bl, gbuf, h0buf[p ^ 1], 512, h1buf[p], 512,
                          wg1, bias1, c1r, h1buf[p ^ 1], row0, j0);
    produce(CH1(p ^ 1));
    // P3: j<8 -> z(t) = fc(h1(t)); j>=8 -> out(t-1) = lin(z(t-1))
    if (j < 8) {
      wait1(CH1(p ^ 1), 16 * full);
      proj_partials<4>(Atp, gbuf, h1buf[p ^ 1], 512, wpj, row0);
      const int m = threadIdx.x >> 3, nb = (threadIdx.x & 7) * 4;
      const int n0 = j * 32;
      short zz[4];
#pragma unroll
      for (int u = 0; u < 4; ++u) {
        int n = nb + u;
        float v = gbuf[(0 * 32 + m) * 32 + n] + gbuf[(1 * 32 + m) * 32 + n] +
                  gbuf[(2 * 32 + m) * 32 + n] + gbuf[(3 * 32 + m) * 32 + n] +
                  fcb[n0 + n];
        zz[u] = f2bf(v);
      }
      ull zv; __builtin_memcpy(&zv, zz, 8);
      *(ull*)&zbuf[p][(size_t)(row0 + m) * 256 + n0 + nb] = zv;
      produce(CZ(p));
    } else if (t > 0) {
      // z(t-1) freshness guaranteed by this step's P1 wait (program order)
      proj_partials<2>(Atp, gbuf, zbuf[p ^ 1], 256, wpj, row0);
      const int m = threadIdx.x >> 3, nb = (threadIdx.x & 7) * 4;
      const int n0 = (j - 8) * 32;
      float4 ov;
      float* po = &ov.x;
#pragma unroll
      for (int u = 0; u < 4; ++u) {
        int n = nb + u;
        po[u] = gbuf[(0 * 32 + m) * 32 + n] + gbuf[(1 * 32 + m) * 32 + n] +
                gbuf[(2 * 32 + m) * 32 + n] + gbuf[(3 * 32 + m) * 32 + n] +
                linb[n0 + n];
      }
      *(float4*)&outp[(size_t)(t - 1) * 262144 + (size_t)(row0 + m) * 256 + n0 + nb] = ov;
    }
  }
  // final out(127) from z(127) in zbuf[1]: z[1] rounds = prep + fc odd t = 65
  if (j >= 8) {
    wait1(CZ(1), 8 * 65);
    proj_partials<2>(Atp, gbuf, zbuf[1], 256, wpj, row0);
    const int m = threadIdx.x >> 3, nb = (threadIdx.x & 7) * 4;
    const int n0 = (j - 8) * 32;
    float4 ov;
    float* po = &ov.x;
#pragma unroll
    for (int u = 0; u < 4; ++u) {
      int n = nb + u;
      po[u] = gbuf[(0 * 32 + m) * 32 + n] + gbuf[(1 * 32 + m) * 32 + n] +
              gbuf[(2 * 32 + m) * 32 + n] + gbuf[(3 * 32 + m) * 32 + n] +
              linb[n0 + n];
    }
    *(float4*)&outp[(size_t)127 * 262144 + (size_t)(row0 + m) * 256 + n0 + nb] = ov;
  }
#undef CZ
#undef CH0
#undef CH1
}

// ---------------------------------------------------------------------------
extern "C" void kernel_launch(void* const* d_in, const int* in_sizes, int n_in,
                              void* d_out, int out_size, void* d_ws, size_t ws_size,
                              hipStream_t stream) {
  const float* z0   = (const float*)d_in[0];
  const float* h0in = (const float*)d_in[1];
  const float* c0in = (const float*)d_in[2];
  const float* Wih0 = (const float*)d_in[3];
  const float* Whh0 = (const float*)d_in[4];
  const float* bih0 = (const float*)d_in[5];
  const float* bhh0 = (const float*)d_in[6];
  const float* Wih1 = (const float*)d_in[7];
  const float* Whh1 = (const float*)d_in[8];
  const float* bih1 = (const float*)d_in[9];
  const float* bhh1 = (const float*)d_in[10];
  const float* fcW  = (const float*)d_in[11];
  const float* fcb  = (const float*)d_in[12];
  const float* linW = (const float*)d_in[13];
  const float* linb = (const float*)d_in[14];
  float* out = (float*)d_out;

  char* ws = (char*)d_ws;
  short* wsw0  = (short*)(ws + 0);         // 3,145,728 B
  short* wsw1  = (short*)(ws + 3145728);   // 4,194,304 B
  short* fcWsw = (short*)(ws + 7340032);   //   262,144 B
  short* linWsw= (short*)(ws + 7602176);   //   131,072 B
  float* bias0 = (float*)(ws + 7733248);   //     8,192 B
  float* bias1 = (float*)(ws + 7741440);   //     8,192 B
  short* zb0   = (short*)(ws + 7749632);   //   524,288 B
  short* zb1   = (short*)(ws + 8273920);   //   524,288 B
  short* h0b0  = (short*)(ws + 8798208);   // 1,048,576 B
  short* h0b1  = (short*)(ws + 9846784);
  short* h1b0  = (short*)(ws + 10895360);
  short* h1b1  = (short*)(ws + 11943936);
  int*   flags = (int*)  (ws + 12992512);  //    33,792 B (total ~13 MB)

  prep_kernel<<<20273, 256, 0, stream>>>(z0, h0in, Wih0, Whh0, bih0, bhh0,
                                         Wih1, Whh1, bih1, bhh1, fcW, linW,
                                         wsw0, wsw1, fcWsw, linWsw, bias0, bias1,
                                         zb1, h0b0, h1b0, flags);

  decoder_persist<<<512, 256, 0, stream>>>(
      wsw0, wsw1, fcWsw, linWsw, bias0, bias1, fcb, linb, c0in,
      h0b0, h0b1, h1b0, h1b1, zb0, zb1, flags, out);
}

// Round 5
// 4819.991 us; speedup vs baseline: 1.8531x; 1.3306x over previous
//
#include <hip/hip_runtime.h>

// Decoder: 2-layer LSTM, B=1024, IN=256, H=512, OUT=256, T2=128 (hardcoded).
// PERSISTENT kernel, 256 blocks x 512 thr, 1 block/CU (~104KB LDS).
// Round-8: M=64 DMA pipeline. 16 batch-groups of 64 rows, 16 j-blocks each,
// XCD-LOCAL (2 groups per XCD), barrier-free dataflow handshakes (r6 scheme).
//   - Cells stream A (activations) and B (weights) via global_load_lds in
//     K=64 granules: B 5-deep, A 3-deep, raw s_barrier + exact in-order
//     vmcnt tiers (warmup 2/4/6, steady 8, taper 6/4/1/0).
//   - M=64 vs r7's 32: halves the weight stream (235->117 MB/step), doubles
//     per-granule MFMA work -> less L2/L3 queueing, better amortization.
//   - B prologue (5 granules, 80KB immutable weights) issued BEFORE the
//     producer-handshake wait: the handshake window streams weights.
//   - proj (fc/lin) A-stages prefetched upfront (1 latency instead of NQ).
//   - weights pre-swizzled to MFMA B-frag order (granule-contiguous 16KB);
//     c-state in VGPRs; activations through XCD-local L2 (plain st/ld +
//     buffer_inv at handshakes).

typedef __attribute__((ext_vector_type(8))) __bf16 bf16x8;
typedef __attribute__((ext_vector_type(16))) float f32x16;
typedef unsigned long long ull;

__device__ __forceinline__ f32x16 mfma_bf16(bf16x8 a, bf16x8 b, f32x16 c) {
  return __builtin_amdgcn_mfma_f32_32x32x16_bf16(a, b, c, 0, 0, 0);
}

__device__ __forceinline__ short f2bf(float f) {  // RNE fp32->bf16
  unsigned u = __float_as_uint(f);
  u += 0x7fffu + ((u >> 16) & 1u);
  return (short)(u >> 16);
}

__device__ __forceinline__ float sigm(float x) { return 1.0f / (1.0f + __expf(-x)); }
__device__ __forceinline__ float tanh_fast(float x) { return 2.0f / (1.0f + __expf(-2.0f * x)) - 1.0f; }

__device__ __forceinline__ f32x16 zero16() {
  f32x16 z;
#pragma unroll
  for (int i = 0; i < 16; ++i) z[i] = 0.0f;
  return z;
}

__device__ __forceinline__ void dma16(const void* g, void* l) {
  __builtin_amdgcn_global_load_lds(
      (const __attribute__((address_space(1))) void*)g,
      (__attribute__((address_space(3))) void*)l, 16, 0, 0);
}

// proj A-tile LDS layout: row m (0..63) at stride 132 shorts (padded).
#define AT_STRIDE 132

// ---------------------------------------------------------------------------
// prep: swizzle weights into MFMA B-frag order (granule-contiguous); sum
// biases; init bf16 states; init ready-counters (cnt[z1]=8, cnt[h0_0]=16,
// cnt[h1_0]=16 — prep is the t=-1 producer); zero the rest + XCD ctrs.
// flags: per group g: flags[g*256 + type*32], type 0=z[0],1=z[1],2=h0[0],
// 3=h0[1],4=h1[0],5=h1[1]. XCD ctrs at 8192+x*32.
// ---------------------------------------------------------------------------
__global__ __launch_bounds__(256) void prep_kernel(
    const float* __restrict__ z0, const float* __restrict__ h0in,
    const float* __restrict__ Wih0, const float* __restrict__ Whh0,
    const float* __restrict__ bih0, const float* __restrict__ bhh0,
    const float* __restrict__ Wih1, const float* __restrict__ Whh1,
    const float* __restrict__ bih1, const float* __restrict__ bhh1,
    const float* __restrict__ fcW, const float* __restrict__ linW,
    short* __restrict__ wsw0, short* __restrict__ wsw1,
    short* __restrict__ fcWsw, short* __restrict__ linWsw,
    float* __restrict__ bias0, float* __restrict__ bias1,
    short* __restrict__ zb1, short* __restrict__ h0b0, short* __restrict__ h1b0,
    int* __restrict__ flags)
{
  int idx = blockIdx.x * 256 + threadIdx.x;
  if (idx < 1572864) {  // wsw0 [j16][s48][g4][l64][8]; K=768 = [z 256 | h0 512]
    int jj = idx & 7, l = (idx >> 3) & 63, gg = (idx >> 9) & 3;
    int rest = idx >> 11;           // j*48 + s
    int s = rest % 48, b = rest / 48;
    int row = gg * 512 + b * 32 + (l & 31);
    int k = s * 16 + (l >> 5) * 8 + jj;
    wsw0[idx] = f2bf(k < 256 ? Wih0[row * 256 + k] : Whh0[row * 512 + (k - 256)]);
    return;
  }
  idx -= 1572864;
  if (idx < 2097152) {  // wsw1 [j16][s64][g4][l64][8]; K=1024 = [h0 512 | h1 512]
    int jj = idx & 7, l = (idx >> 3) & 63, gg = (idx >> 9) & 3;
    int rest = idx >> 11;           // j*64 + s
    int s = rest & 63, b = rest >> 6;
    int row = gg * 512 + b * 32 + (l & 31);
    int k = s * 16 + (l >> 5) * 8 + jj;
    wsw1[idx] = f2bf(k < 512 ? Wih1[row * 512 + k] : Whh1[row * 512 + (k - 512)]);
    return;
  }
  idx -= 2097152;
  if (idx < 131072) {  // fcWsw [jz8][s32][l64][8]
    int jj = idx & 7, l = (idx >> 3) & 63, s = (idx >> 9) & 31, jz = idx >> 14;
    int col = jz * 32 + (l & 31);
    int k = s * 16 + (l >> 5) * 8 + jj;
    fcWsw[idx] = f2bf(fcW[col * 512 + k]);
    return;
  }
  idx -= 131072;
  if (idx < 65536) {  // linWsw [jo8][s16][l64][8]
    int jj = idx & 7, l = (idx >> 3) & 63, s = (idx >> 9) & 15, jo = idx >> 13;
    int col = jo * 32 + (l & 31);
    int k = s * 16 + (l >> 5) * 8 + jj;
    linWsw[idx] = f2bf(linW[col * 256 + k]);
    return;
  }
  idx -= 65536;
  if (idx < 2048) { bias0[idx] = bih0[idx] + bhh0[idx]; return; }
  idx -= 2048;
  if (idx < 2048) { bias1[idx] = bih1[idx] + bhh1[idx]; return; }
  idx -= 2048;
  if (idx < 262144) { zb1[idx] = f2bf(z0[idx]); return; }
  idx -= 262144;
  if (idx < 524288) { h0b0[idx] = f2bf(h0in[idx]); return; }
  idx -= 524288;
  if (idx < 524288) { h1b0[idx] = f2bf(h0in[524288 + idx]); return; }
  idx -= 524288;
  if (idx < 8448) {  // ready-counters + xcd ctrs
    int v = 0;
    if (idx < 8192) {
      int off = idx & 255;
      if (off == 32) v = 8;                       // cnt_z[1] (prep wrote zb1)
      else if (off == 64 || off == 128) v = 16;   // cnt_h0[0], cnt_h1[0]
    }
    flags[idx] = v;
    return;
  }
}

// ---------------------------------------------------------------------------
// Dataflow sync: producers add 1 (after vmcnt drain); consumers poll to a
// monotone target, then buffer_inv (per-CU L1 invalidate; XCD L2 stays warm).
// ---------------------------------------------------------------------------
__device__ __forceinline__ void wait1(int* c0, int v0) {
  __syncthreads();
  if (threadIdx.x == 0) {
    while (__hip_atomic_load(c0, __ATOMIC_RELAXED, __HIP_MEMORY_SCOPE_AGENT) < v0)
      __builtin_amdgcn_s_sleep(2);
    asm volatile("buffer_inv" ::: "memory");
  }
  __syncthreads();
}

__device__ __forceinline__ void wait2(int* c0, int v0, int* c1, int v1) {
  __syncthreads();
  if (threadIdx.x == 0) {
    while (__hip_atomic_load(c0, __ATOMIC_RELAXED, __HIP_MEMORY_SCOPE_AGENT) < v0 ||
           __hip_atomic_load(c1, __ATOMIC_RELAXED, __HIP_MEMORY_SCOPE_AGENT) < v1)
      __builtin_amdgcn_s_sleep(2);
    asm volatile("buffer_inv" ::: "memory");
  }
  __syncthreads();
}

__device__ __forceinline__ void produce(int* c) {
  asm volatile("s_waitcnt vmcnt(0)" ::: "memory");
  __syncthreads();
  if (threadIdx.x == 0)
    __hip_atomic_fetch_add(c, 1, __ATOMIC_RELAXED, __HIP_MEMORY_SCOPE_AGENT);
}

// ---------------------------------------------------------------------------
// Warm: issue the first 5 B-weight granules (80KB, immutable) BEFORE the
// handshake wait. Leading __syncthreads closes previous gbuf/Atp readers of
// the aliased Bl region. vmcnt accounting handled by the tiers in the cell.
// ---------------------------------------------------------------------------
__device__ __forceinline__ void cell_warm(short* Bl, const short* __restrict__ wgl) {
  __syncthreads();
  const int t = threadIdx.x, w = t >> 6;
#pragma unroll
  for (int g = 0; g < 5; ++g)
#pragma unroll
    for (int i = 0; i < 2; ++i)
      dma16(wgl + (size_t)g * 8192 + (i * 512 + t) * 8,
            Bl + g * 8192 + i * 4096 + w * 512);
}

// ---------------------------------------------------------------------------
// DMA-pipelined LSTM cell phase (M=64, K granule = 64, 512 threads).
//   A LDS (K-major, 8KB/granule): slot ((k8)*64+row)*8 shorts, 3 buffers.
//   B LDS: granule 16KB = [u4][gate4][l64][8 shorts], 5 buffers (0..4 warmed).
//   Per iter g: wait tier -> barrier -> 4 MFMAs/wave -> barrier ->
//   issue A(g+3), B(g+5). Exact in-order vmcnt tiers (see derivation).
// ---------------------------------------------------------------------------
template <int NG, int TAG>
__device__ __forceinline__ void cell_phase_dma(
    short* Al, short* Bl, float* gbuf,
    const short* __restrict__ srcA, int ldA,
    const short* __restrict__ srcB, int ldB,
    const short* __restrict__ wgl,
    const float* __restrict__ bias,
    float* cr, short* hout, int row0, int j0)
{
  const int t = threadIdx.x;           // 0..511, 8 waves
  const int w = t >> 6, l = t & 63;
  const int gq = w >> 1, mh = w & 1;   // wave = (gate quadrant, m-half)
  const int ln = l & 31, kh = l >> 5;

  auto issueA = [&](int g) {
    const short* asrc; int ald, gk;
    if (g < TAG) { asrc = srcA; ald = ldA; gk = g * 64; }
    else         { asrc = srcB; ald = ldB; gk = (g - TAG) * 64; }
    // wave w loads k8-slice w for all 64 rows (lane = row)
    const short* gp = asrc + (size_t)(row0 + l) * ald + gk + w * 8;
    dma16(gp, Al + (g % 3) * 4096 + w * 512);
  };
  auto issueB = [&](int g) {
    const short* gb = wgl + (size_t)g * 8192;
    short* lb = Bl + (g % 5) * 8192;
#pragma unroll
    for (int i = 0; i < 2; ++i)
      dma16(gb + (i * 512 + t) * 8, lb + i * 4096 + w * 512);
  };

  f32x16 acc = zero16();
  // A prologue (B0..B4 already issued by cell_warm, BEFORE the handshake)
  issueA(0); issueA(1); issueA(2);

#pragma unroll
  for (int g = 0; g < NG; ++g) {
    // exact in-order vmcnt: A(g),B(g) complete when <= tier remain.
    if (g == 0)          asm volatile("s_waitcnt vmcnt(2)" ::: "memory");
    else if (g == 1)     asm volatile("s_waitcnt vmcnt(4)" ::: "memory");
    else if (g == 2)     asm volatile("s_waitcnt vmcnt(6)" ::: "memory");
    else if (g + 4 < NG) asm volatile("s_waitcnt vmcnt(8)" ::: "memory");
    else if (g + 3 < NG) asm volatile("s_waitcnt vmcnt(6)" ::: "memory");
    else if (g + 2 < NG) asm volatile("s_waitcnt vmcnt(4)" ::: "memory");
    else if (g + 1 < NG) asm volatile("s_waitcnt vmcnt(1)" ::: "memory");
    else                 asm volatile("s_waitcnt vmcnt(0)" ::: "memory");
    __builtin_amdgcn_s_barrier();          // granule g fully in LDS (all waves)
    __builtin_amdgcn_sched_barrier(0);
    const short* al = Al + (g % 3) * 4096;
    const short* bl = Bl + (g % 5) * 8192;
#pragma unroll
    for (int u = 0; u < 4; ++u) {
      bf16x8 a = *(const bf16x8*)&al[((u * 2 + kh) * 64 + mh * 32 + ln) * 8];
      bf16x8 b = *(const bf16x8*)&bl[((u * 4 + gq) * 64 + l) * 8];
      acc = mfma_bf16(a, b, acc);
    }
    __builtin_amdgcn_sched_barrier(0);
    __builtin_amdgcn_s_barrier();          // all waves done reading granule g
    __builtin_amdgcn_sched_barrier(0);
    if (g + 3 < NG) issueA(g + 3);         // refills A slot just read
    if (g + 5 < NG) issueB(g + 5);         // refills B slot just read
  }

  // C layout: col = lane&31, row = (r&3)+8*(r>>2)+4*(lane>>5) (+32 for mh=1).
  // gbuf aliases B buffers (pipeline drained: vmcnt(0) at g=NG-1 + barrier).
#pragma unroll
  for (int r = 0; r < 16; ++r) {
    int mloc = (r & 3) + 8 * (r >> 2) + 4 * kh + mh * 32;
    gbuf[(gq * 64 + mloc) * 32 + ln] = acc[r];
  }
  __syncthreads();
  const int m = t >> 3, nb = (t & 7) * 4;  // m 0..63, nb 0..28
  short hh[4];
#pragma unroll
  for (int u = 0; u < 4; ++u) {
    int n = nb + u, jn = j0 + n;
    float gi = gbuf[(0 * 64 + m) * 32 + n] + bias[jn];
    float gf = gbuf[(1 * 64 + m) * 32 + n] + bias[512 + jn];
    float gg = gbuf[(2 * 64 + m) * 32 + n] + bias[1024 + jn];
    float go = gbuf[(3 * 64 + m) * 32 + n] + bias[1536 + jn];
    float cn = sigm(gf) * cr[u] + sigm(gi) * tanh_fast(gg);
    cr[u] = cn;
    hh[u] = f2bf(sigm(go) * tanh_fast(cn));
  }
  ull hv; __builtin_memcpy(&hv, hh, 8);
  *(ull*)&hout[(size_t)(row0 + m) * 512 + j0 + nb] = hv;  // plain: same-XCD L2
}

// ---------------------------------------------------------------------------
// Projection partials (fc or lin), M=64, 512 thr: waves (kq = w>>1, mh = w&1).
// ALL q A-stage loads prefetched upfront (one latency, not NQ). B streamed
// from global (small, L2-hot). 4 K-partials land in gbuf[kq][m][n].
// ---------------------------------------------------------------------------
template <int NQ>
__device__ __forceinline__ void proj_partials(
    short* At0, float* gbuf,
    const short* __restrict__ src, int ld,
    const short* __restrict__ wblk, int row0)
{
  const int t = threadIdx.x;
  const int w = t >> 6, l = t & 63;
  const int kq = w >> 1, mh = w & 1;
  const int ln = l & 31, kh = l >> 5;
  const int sks = t & 15, sm = t >> 4;   // staging: ks 0..15, m 0..31 (+32)
  f32x16 acc = zero16();
  uint4 pre[NQ][2];
#pragma unroll
  for (int q = 0; q < NQ; ++q)
#pragma unroll
    for (int i = 0; i < 2; ++i)
      pre[q][i] = *(const uint4*)&src[(row0 + sm + 32 * i) * ld + q * 128 + sks * 8];
#pragma unroll
  for (int q = 0; q < NQ; ++q) {
    __syncthreads();
#pragma unroll
    for (int i = 0; i < 2; ++i)
      *(uint4*)&At0[(sm + 32 * i) * AT_STRIDE + sks * 8] = pre[q][i];
    __syncthreads();
#pragma unroll
    for (int sl = 0; sl < 2; ++sl) {
      int s16 = kq * 2 + sl;
      bf16x8 a = *(const bf16x8*)&At0[(mh * 32 + ln) * AT_STRIDE + (s16 * 2 + kh) * 8];
      bf16x8 b = *(const bf16x8*)&wblk[((q * 8 + s16) * 64 + l) * 8];
      acc = mfma_bf16(a, b, acc);
    }
  }
  __syncthreads();
#pragma unroll
  for (int r = 0; r < 16; ++r) {
    int mloc = (r & 3) + 8 * (r >> 2) + 4 * kh + mh * 32;
    gbuf[(kq * 64 + mloc) * 32 + ln] = acc[r];
  }
  __syncthreads();
}

__global__ __launch_bounds__(512, 1) void decoder_persist(
    const short* __restrict__ wsw0, const short* __restrict__ wsw1,
    const short* __restrict__ fcWsw, const short* __restrict__ linWsw,
    const float* __restrict__ bias0, const float* __restrict__ bias1,
    const float* __restrict__ fcb, const float* __restrict__ linb,
    const float* __restrict__ c0in,
    short* h0x, short* h0y, short* h1x, short* h1y, short* zx, short* zy,
    int* flags, float* __restrict__ outp)
{
  __shared__ __align__(16) short Al[12288];   // 24 KB: A granules, 3 buffers
  __shared__ __align__(16) short Bl[40960];   // 80 KB: B granules, 5 buffers
  __shared__ int sgj[2];
  float* gbuf = (float*)Bl;                   // 32 KB cell gbuf, aliases B
  short* Atp = Bl;                            // proj A-stage (16896 B)
  float* gbufp = (float*)(Bl + 8448);         // proj gbuf (32 KB), after Atp

  // --- self-assignment: physical XCD id -> (group, j) slot ---
  if (threadIdx.x == 0) {
    unsigned xcc;
    asm volatile("s_getreg_b32 %0, hwreg(HW_REG_XCC_ID, 0, 32)" : "=s"(xcc));
    xcc &= 7u;
    int slot = __hip_atomic_fetch_add(&flags[8192 + (int)xcc * 32], 1,
                                      __ATOMIC_RELAXED, __HIP_MEMORY_SCOPE_AGENT);
    slot &= 31;                           // hardening: wrong-answer > hang
    sgj[0] = (int)xcc * 2 + (slot >> 4);  // group: 2 per XCD
    sgj[1] = slot & 15;                   // j-tile within group
  }
  __syncthreads();
  const int g = sgj[0], j = sgj[1];
  const int row0 = g * 64, j0 = j * 32;
  int* cnt = &flags[g * 256];             // 6 counters, one cacheline each
#define CZ(i)  (cnt + (0 + (i)) * 32)
#define CH0(i) (cnt + (2 + (i)) * 32)
#define CH1(i) (cnt + (4 + (i)) * 32)

  // --- c-state in registers for the whole run ---
  float c0r[4], c1r[4];
  {
    const int m = threadIdx.x >> 3, nb = (threadIdx.x & 7) * 4;
#pragma unroll
    for (int u = 0; u < 4; ++u) {
      c0r[u] = c0in[(size_t)(row0 + m) * 512 + j0 + nb + u];
      c1r[u] = c0in[524288 + (size_t)(row0 + m) * 512 + j0 + nb + u];
    }
  }

  short* h0buf[2] = {h0x, h0y};
  short* h1buf[2] = {h1x, h1y};
  short* zbuf[2] = {zx, zy};
  const short* wg0 = wsw0 + j * 98304;
  const short* wg1 = wsw1 + j * 131072;
  const short* wpj = (j < 8) ? (fcWsw + j * 16384) : (linWsw + (j - 8) * 8192);

#pragma unroll 1
  for (int t = 0; t < 128; ++t) {
    const int p = t & 1;
    const int half = (t >> 1) + 1;        // completed write-rounds, t-1 parity
    const int full = (t + 3) >> 1;        // incl. this step
    // P1: cell0  (K = [z 256 | h0 512]); weights warm across the handshake
    cell_warm(Bl, wg0);
    wait2(CZ(p ^ 1), 8 * half, CH0(p), 16 * half);
    cell_phase_dma<12, 4>(Al, Bl, gbuf, zbuf[p ^ 1], 256, h0buf[p], 512,
                          wg0, bias0, c0r, h0buf[p ^ 1], row0, j0);
    produce(CH0(p ^ 1));
    // P2: cell1  (K = [h0(t) 512 | h1(t-1) 512])
    cell_warm(Bl, wg1);
    wait2(CH0(p ^ 1), 16 * full, CH1(p), 16 * half);
    cell_phase_dma<16, 8>(Al, Bl, gbuf, h0buf[p ^ 1], 512, h1buf[p], 512,
                          wg1, bias1, c1r, h1buf[p ^ 1], row0, j0);
    produce(CH1(p ^ 1));
    // P3: j<8 -> z(t) = fc(h1(t)); j>=8 -> out(t-1) = lin(z(t-1))
    if (j < 8) {
      wait1(CH1(p ^ 1), 16 * full);
      proj_partials<4>(Atp, gbufp, h1buf[p ^ 1], 512, wpj, row0);
      const int m = threadIdx.x >> 3, nb = (threadIdx.x & 7) * 4;
      const int n0 = j * 32;
      short zz[4];
#pragma unroll
      for (int u = 0; u < 4; ++u) {
        int n = nb + u;
        float v = gbufp[(0 * 64 + m) * 32 + n] + gbufp[(1 * 64 + m) * 32 + n] +
                  gbufp[(2 * 64 + m) * 32 + n] + gbufp[(3 * 64 + m) * 32 + n] +
                  fcb[n0 + n];
        zz[u] = f2bf(v);
      }
      ull zv; __builtin_memcpy(&zv, zz, 8);
      *(ull*)&zbuf[p][(size_t)(row0 + m) * 256 + n0 + nb] = zv;
      produce(CZ(p));
    } else if (t > 0) {
      // z(t-1) freshness guaranteed by this step's P1 wait (program order)
      proj_partials<2>(Atp, gbufp, zbuf[p ^ 1], 256, wpj, row0);
      const int m = threadIdx.x >> 3, nb = (threadIdx.x & 7) * 4;
      const int n0 = (j - 8) * 32;
      float4 ov;
      float* po = &ov.x;
#pragma unroll
      for (int u = 0; u < 4; ++u) {
        int n = nb + u;
        po[u] = gbufp[(0 * 64 + m) * 32 + n] + gbufp[(1 * 64 + m) * 32 + n] +
                gbufp[(2 * 64 + m) * 32 + n] + gbufp[(3 * 64 + m) * 32 + n] +
                linb[n0 + n];
      }
      *(float4*)&outp[(size_t)(t - 1) * 262144 + (size_t)(row0 + m) * 256 + n0 + nb] = ov;
    }
  }
  // final out(127) from z(127) in zbuf[1]: z[1] rounds = prep + fc odd t = 65
  if (j >= 8) {
    wait1(CZ(1), 8 * 65);
    proj_partials<2>(Atp, gbufp, zbuf[1], 256, wpj, row0);
    const int m = threadIdx.x >> 3, nb = (threadIdx.x & 7) * 4;
    const int n0 = (j - 8) * 32;
    float4 ov;
    float* po = &ov.x;
#pragma unroll
    for (int u = 0; u < 4; ++u) {
      int n = nb + u;
      po[u] = gbufp[(0 * 64 + m) * 32 + n] + gbufp[(1 * 64 + m) * 32 + n] +
              gbufp[(2 * 64 + m) * 32 + n] + gbufp[(3 * 64 + m) * 32 + n] +
              linb[n0 + n];
    }
    *(float4*)&outp[(size_t)127 * 262144 + (size_t)(row0 + m) * 256 + n0 + nb] = ov;
  }
#undef CZ
#undef CH0
#undef CH1
}

// ---------------------------------------------------------------------------
extern "C" void kernel_launch(void* const* d_in, const int* in_sizes, int n_in,
                              void* d_out, int out_size, void* d_ws, size_t ws_size,
                              hipStream_t stream) {
  const float* z0   = (const float*)d_in[0];
  const float* h0in = (const float*)d_in[1];
  const float* c0in = (const float*)d_in[2];
  const float* Wih0 = (const float*)d_in[3];
  const float* Whh0 = (const float*)d_in[4];
  const float* bih0 = (const float*)d_in[5];
  const float* bhh0 = (const float*)d_in[6];
  const float* Wih1 = (const float*)d_in[7];
  const float* Whh1 = (const float*)d_in[8];
  const float* bih1 = (const float*)d_in[9];
  const float* bhh1 = (const float*)d_in[10];
  const float* fcW  = (const float*)d_in[11];
  const float* fcb  = (const float*)d_in[12];
  const float* linW = (const float*)d_in[13];
  const float* linb = (const float*)d_in[14];
  float* out = (float*)d_out;

  char* ws = (char*)d_ws;
  short* wsw0  = (short*)(ws + 0);         // 3,145,728 B
  short* wsw1  = (short*)(ws + 3145728);   // 4,194,304 B
  short* fcWsw = (short*)(ws + 7340032);   //   262,144 B
  short* linWsw= (short*)(ws + 7602176);   //   131,072 B
  float* bias0 = (float*)(ws + 7733248);   //     8,192 B
  float* bias1 = (float*)(ws + 7741440);   //     8,192 B
  short* zb0   = (short*)(ws + 7749632);   //   524,288 B
  short* zb1   = (short*)(ws + 8273920);   //   524,288 B
  short* h0b0  = (short*)(ws + 8798208);   // 1,048,576 B
  short* h0b1  = (short*)(ws + 9846784);
  short* h1b0  = (short*)(ws + 10895360);
  short* h1b1  = (short*)(ws + 11943936);
  int*   flags = (int*)  (ws + 12992512);  //    33,792 B (total ~13 MB)

  prep_kernel<<<20273, 256, 0, stream>>>(z0, h0in, Wih0, Whh0, bih0, bhh0,
                                         Wih1, Whh1, bih1, bhh1, fcW, linW,
                                         wsw0, wsw1, fcWsw, linWsw, bias0, bias1,
                                         zb1, h0b0, h1b0, flags);

  decoder_persist<<<256, 512, 0, stream>>>(
      wsw0, wsw1, fcWsw, linWsw, bias0, bias1, fcb, linb, c0in,
      h0b0, h0b1, h1b0, h1b1, zb0, zb1, flags, out);
}